// Round 4
// baseline (109.820 us; speedup 1.0000x reference)
//
#include <hip/hip_runtime.h>
#include <hip/hip_bf16.h>
#include <math.h>

// Problem constants (fixed by reference setup_inputs)
#define DH 48
#define DW 48
#define DT 48
#define DC 32
#define NPOS (DH * DW * DT)
#define TSLOTS 50  // t in [-1, 48] -> slots 0..49 (zero-padded ends)

// Block = one (h,w) t-row: 48 positions x 8 lanes = 384 threads.
// Stage the 9 spatial-neighbor k-rows in LDS ([9][50][32] f32, 57.6 KB),
// then branch-free compute: each lane owns 4 channels (one float4).
__global__ __launch_bounds__(384) void cotr_natt_kernel(
    const float* __restrict__ q,
    const float* __restrict__ k,
    float* __restrict__ out)
{
    __shared__ float kl[9 * TSLOTS * DC];  // 57600 B

    const int h = blockIdx.x / DW;
    const int w = blockIdx.x - h * DW;
    const int tid = threadIdx.x;

    // ---- stage: 9 rows x 48 t x 32 ch; one float4 per thread per row ----
    const int st = tid >> 3;  // t within row, 0..47
    const int sc = tid & 7;   // float4 channel group, 0..7
#pragma unroll
    for (int r = 0; r < 9; ++r) {
        const int hh = h + r / 3 - 1;
        const int ww = w + r % 3 - 1;
        float4 v = make_float4(0.f, 0.f, 0.f, 0.f);
        if (((unsigned)hh < DH) & ((unsigned)ww < DW)) {
            v = *reinterpret_cast<const float4*>(
                k + ((size_t)(hh * DW + ww) * DT + st) * DC + sc * 4);
        }
        // dst byte addr = base + 16*tid -> conflict-free ds_write_b128
        *reinterpret_cast<float4*>(&kl[(r * TSLOTS + 1 + st) * DC + sc * 4]) = v;
    }
    // zero the two pad t-slots per row: 9 rows * 2 slots * 8 float4 = 144
    if (tid < 144) {
        const int r = tid >> 4;
        const int rem = tid & 15;
        const int slot = (rem >> 3) ? (TSLOTS - 1) : 0;
        const int c4 = rem & 7;
        *reinterpret_cast<float4*>(&kl[(r * TSLOTS + slot) * DC + c4 * 4]) =
            make_float4(0.f, 0.f, 0.f, 0.f);
    }
    __syncthreads();

    // ---- compute: position t = tid>>3, channel quad sub = tid&7 ----
    const int t = tid >> 3;
    const int sub = tid & 7;
    const int idx = (h * DW + w) * DT + t;

    const float4 qv =
        *reinterpret_cast<const float4*>(q + (size_t)idx * DC + sub * 4);

    // 27 per-lane partial dots (4 channels each), fully branch-free.
    float part[27];
#pragma unroll
    for (int r = 0; r < 9; ++r) {
#pragma unroll
        for (int c = 0; c < 3; ++c) {
            // slot for tt = t + c - 1 is tt + 1 = t + c; lane addr = base+16*lane
            const float4 kv = *reinterpret_cast<const float4*>(
                &kl[(r * TSLOTS + t + c) * DC + sub * 4]);
            part[r * 3 + c] =
                fmaf(qv.x, kv.x,
                fmaf(qv.y, kv.y,
                fmaf(qv.z, kv.z, qv.w * kv.w)));
        }
    }

    // reduce across the 8-lane channel group (butterfly -> all lanes full)
    float m = -INFINITY;
#pragma unroll
    for (int j = 0; j < 27; ++j) {
        float v = part[j];
        v += __shfl_xor(v, 1, 64);
        v += __shfl_xor(v, 2, 64);
        v += __shfl_xor(v, 4, 64);
        part[j] = v;
        m = fmaxf(m, v);
    }

    // softmax over 27 + displacement-weighted sum
    float sum = 0.0f;
    float oh = 0.0f, ow = 0.0f, ot = 0.0f;
#pragma unroll
    for (int j = 0; j < 27; ++j) {
        const float e = __expf(part[j] - m);
        sum += e;
        const float da = (float)(j / 9 - 1);
        const float db = (float)((j / 3) % 3 - 1);
        const float dc = (float)(j % 3 - 1);
        oh = fmaf(e, da, oh);
        ow = fmaf(e, db, ow);
        ot = fmaf(e, dc, ot);
    }
    const float inv = 1.0f / sum;

    // Output layout [B, 3, H, W, T]; lanes 0/1/2 of each group write dh/dw/dt.
    if (sub == 0)      out[0 * NPOS + idx] = oh * inv;
    else if (sub == 1) out[1 * NPOS + idx] = ow * inv;
    else if (sub == 2) out[2 * NPOS + idx] = ot * inv;
}

extern "C" void kernel_launch(void* const* d_in, const int* in_sizes, int n_in,
                              void* d_out, int out_size, void* d_ws, size_t ws_size,
                              hipStream_t stream) {
    const float* q = reinterpret_cast<const float*>(d_in[0]);
    const float* k = reinterpret_cast<const float*>(d_in[1]);
    float* out = reinterpret_cast<float*>(d_out);

    const int threads = 384;     // 48 positions * 8 lanes
    const int blocks = DH * DW;  // one (h,w) t-row per block
    cotr_natt_kernel<<<blocks, threads, 0, stream>>>(q, k, out);
}

// Round 5
// 94.492 us; speedup vs baseline: 1.1622x; 1.1622x over previous
//
#include <hip/hip_runtime.h>
#include <hip/hip_bf16.h>
#include <math.h>

// Problem constants (fixed by reference setup_inputs)
#define DH 48
#define DW 48
#define DT 48
#define DC 32
#define NPOS (DH * DW * DT)

// Block = one (h,w) t-row: 48 positions x 8 lanes = 384 threads, NO LDS.
// Each lane owns 4 channels (one float4); k read straight from global
// (L1 absorbs the 27x neighborhood re-reads; FETCH_SIZE stays compulsory).
__global__ __launch_bounds__(384) void cotr_natt_kernel(
    const float* __restrict__ q,
    const float* __restrict__ k,
    float* __restrict__ out)
{
    const int h = blockIdx.x / DW;
    const int w = blockIdx.x - h * DW;
    const int t = threadIdx.x >> 3;   // position within the t-row, 0..47
    const int sub = threadIdx.x & 7;  // channel quad, 0..7

    const int idx = (h * DW + w) * DT + t;

    const float4 qv =
        *reinterpret_cast<const float4*>(q + (size_t)idx * DC + sub * 4);

    // 27 per-lane partial dots (4 channels each). All loads independent ->
    // deep memory-level parallelism; invalid neighbors contribute score 0
    // (zero-pad semantics of the reference).
    float part[27];
#pragma unroll
    for (int a = 0; a < 3; ++a) {
        const int hh = h + a - 1;
        const bool va = ((unsigned)hh < DH);
#pragma unroll
        for (int b = 0; b < 3; ++b) {
            const int ww = w + b - 1;
            const bool vab = va && ((unsigned)ww < DW);
            const float* krow = k + (size_t)(hh * DW + ww) * DT * DC;
#pragma unroll
            for (int c = 0; c < 3; ++c) {
                const int tt = t + c - 1;
                const int j = (a * 3 + b) * 3 + c;
                float s = 0.0f;
                if (vab & ((unsigned)tt < DT)) {
                    const float4 kv = *reinterpret_cast<const float4*>(
                        krow + (size_t)tt * DC + sub * 4);
                    s = fmaf(qv.x, kv.x,
                        fmaf(qv.y, kv.y,
                        fmaf(qv.z, kv.z, qv.w * kv.w)));
                }
                part[j] = s;
            }
        }
    }

    // Butterfly-reduce the 8-lane channel group; every lane ends with the
    // full 27 scores, then does the tiny softmax redundantly.
    float m = -INFINITY;
#pragma unroll
    for (int j = 0; j < 27; ++j) {
        float v = part[j];
        v += __shfl_xor(v, 1, 64);
        v += __shfl_xor(v, 2, 64);
        v += __shfl_xor(v, 4, 64);
        part[j] = v;
        m = fmaxf(m, v);
    }

    float sum = 0.0f;
    float oh = 0.0f, ow = 0.0f, ot = 0.0f;
#pragma unroll
    for (int j = 0; j < 27; ++j) {
        const float e = __expf(part[j] - m);
        sum += e;
        const float da = (float)(j / 9 - 1);
        const float db = (float)((j / 3) % 3 - 1);
        const float dc = (float)(j % 3 - 1);
        oh = fmaf(e, da, oh);
        ow = fmaf(e, db, ow);
        ot = fmaf(e, dc, ot);
    }
    const float inv = 1.0f / sum;

    // Output layout [B, 3, H, W, T]; lanes 0/1/2 of each group write dh/dw/dt.
    if (sub == 0)      out[0 * NPOS + idx] = oh * inv;
    else if (sub == 1) out[1 * NPOS + idx] = ow * inv;
    else if (sub == 2) out[2 * NPOS + idx] = ot * inv;
}

extern "C" void kernel_launch(void* const* d_in, const int* in_sizes, int n_in,
                              void* d_out, int out_size, void* d_ws, size_t ws_size,
                              hipStream_t stream) {
    const float* q = reinterpret_cast<const float*>(d_in[0]);
    const float* k = reinterpret_cast<const float*>(d_in[1]);
    float* out = reinterpret_cast<float*>(d_out);

    const int threads = 384;     // 48 positions * 8 lanes
    const int blocks = DH * DW;  // one (h,w) t-row per block
    cotr_natt_kernel<<<blocks, threads, 0, stream>>>(q, k, out);
}

// Round 6
// 84.250 us; speedup vs baseline: 1.3035x; 1.1216x over previous
//
#include <hip/hip_runtime.h>
#include <hip/hip_bf16.h>
#include <math.h>

// Problem constants (fixed by reference setup_inputs)
#define DH 48
#define DW 48
#define DT 48
#define DC 32
#define NPOS (DH * DW * DT)

// Block = one (h,w) t-row: 48 positions x 8 lanes = 384 threads, no LDS.
// ALL 27 neighbor loads are branch-free (clamped address + post-hoc 0/1
// scale) so the compiler can keep many loads in flight (MLP), instead of
// the 1-outstanding-load serialization the predicated version produced.
__global__ __launch_bounds__(384) void cotr_natt_kernel(
    const float* __restrict__ q,
    const float* __restrict__ k,
    float* __restrict__ out)
{
    const int h = blockIdx.x / DW;
    const int w = blockIdx.x - h * DW;
    const int t = threadIdx.x >> 3;   // position within the t-row, 0..47
    const int sub = threadIdx.x & 7;  // channel quad, 0..7

    const int idx = (h * DW + w) * DT + t;

    const float4 qv =
        *reinterpret_cast<const float4*>(q + (size_t)idx * DC + sub * 4);

    // Block-uniform spatial rows: clamped base + 0/1 validity (stays scalar).
    int rowbase[9];
    float rowscale[9];
#pragma unroll
    for (int r = 0; r < 9; ++r) {
        const int hh = h + r / 3 - 1;
        const int ww = w + r % 3 - 1;
        const bool v = ((unsigned)hh < DH) & ((unsigned)ww < DW);
        const int hc = min(max(hh, 0), DH - 1);
        const int wc = min(max(ww, 0), DW - 1);
        rowbase[r] = (hc * DW + wc) * DT;
        rowscale[r] = v ? 1.0f : 0.0f;
    }

    // Per-lane t: clamped index + 0/1 validity.
    int tc[3];
    float tscale[3];
#pragma unroll
    for (int c = 0; c < 3; ++c) {
        const int tt = t + c - 1;
        tc[c] = min(max(tt, 0), DT - 1);
        tscale[c] = ((unsigned)tt < DT) ? 1.0f : 0.0f;
    }

    // 27 unconditional partial dots (4 channels per lane). No branches ->
    // loads issue back-to-back; clamped loads read real (finite) k values
    // and are zeroed by the scale below, matching zero-pad semantics.
    float part[27];
#pragma unroll
    for (int r = 0; r < 9; ++r) {
#pragma unroll
        for (int c = 0; c < 3; ++c) {
            const float4 kv = *reinterpret_cast<const float4*>(
                k + (size_t)(rowbase[r] + tc[c]) * DC + sub * 4);
            part[r * 3 + c] =
                fmaf(qv.x, kv.x,
                fmaf(qv.y, kv.y,
                fmaf(qv.z, kv.z, qv.w * kv.w)));
        }
    }

    // Butterfly-reduce the 8-lane channel group, then apply validity scale.
    float m = -INFINITY;
#pragma unroll
    for (int j = 0; j < 27; ++j) {
        float v = part[j];
        v += __shfl_xor(v, 1, 64);
        v += __shfl_xor(v, 2, 64);
        v += __shfl_xor(v, 4, 64);
        v *= rowscale[j / 3] * tscale[j % 3];
        part[j] = v;
        m = fmaxf(m, v);
    }

    // Softmax over 27 + displacement-weighted sum (j = a*9 + b*3 + c).
    float sum = 0.0f;
    float oh = 0.0f, ow = 0.0f, ot = 0.0f;
#pragma unroll
    for (int j = 0; j < 27; ++j) {
        const float e = __expf(part[j] - m);
        sum += e;
        const float da = (float)(j / 9 - 1);
        const float db = (float)((j / 3) % 3 - 1);
        const float dc = (float)(j % 3 - 1);
        oh = fmaf(e, da, oh);
        ow = fmaf(e, db, ow);
        ot = fmaf(e, dc, ot);
    }
    const float inv = 1.0f / sum;

    // Output layout [B, 3, H, W, T]; lanes 0/1/2 of each group write dh/dw/dt.
    if (sub == 0)      out[0 * NPOS + idx] = oh * inv;
    else if (sub == 1) out[1 * NPOS + idx] = ow * inv;
    else if (sub == 2) out[2 * NPOS + idx] = ot * inv;
}

extern "C" void kernel_launch(void* const* d_in, const int* in_sizes, int n_in,
                              void* d_out, int out_size, void* d_ws, size_t ws_size,
                              hipStream_t stream) {
    const float* q = reinterpret_cast<const float*>(d_in[0]);
    const float* k = reinterpret_cast<const float*>(d_in[1]);
    float* out = reinterpret_cast<float*>(d_out);

    const int threads = 384;     // 48 positions * 8 lanes
    const int blocks = DH * DW;  // one (h,w) t-row per block
    cotr_natt_kernel<<<blocks, threads, 0, stream>>>(q, k, out);
}